// Round 18
// baseline (68.040 us; speedup 1.0000x reference)
//
#include <hip/hip_runtime.h>

// Per-row MLP 5->120->84->5 + relu + L2-normalize + x!=0 mask.
// R18 = R17 + explicit 1-deep cross-pair software pipeline in mfma_main:
//   iter p: [L2(p) | consume x(p+nw)->ax/masks, prefetch x(p+2nw)]
//           [pack+L3(p)] [L1(p+nw)+pack  <- fills L3's latency]
//           [epilogue(p) <- overlaps next iter's L2]
// x values replaced by 5-bit nonzero-masks after ax construction (only use
// of x post-L1 is the x!=0 mask) to keep peak regs ~250 (2 waves/SIMD).
// Everything else (K16 L1, cvt_pkrtz+pk_max packs, zero-C accs, rsq
// epilogue, setprio, wave-parallel rescue) unchanged from R17.

typedef _Float16 f16x8 __attribute__((ext_vector_type(8)));
typedef _Float16 f16x4 __attribute__((ext_vector_type(4)));
typedef __fp16   hf16x2 __attribute__((ext_vector_type(2)));
typedef float    f32x4 __attribute__((ext_vector_type(4)));

#define MFMA32(a, b, c) __builtin_amdgcn_mfma_f32_16x16x32_f16((a), (b), (c), 0, 0, 0)
#define FZERO ((f32x4){0.f, 0.f, 0.f, 0.f})

#if __has_builtin(__builtin_amdgcn_mfma_f32_16x16x16f16)
#define MFMA16(a, b, c) __builtin_amdgcn_mfma_f32_16x16x16f16((a), (b), (c), 0, 0, 0)
#elif __has_builtin(__builtin_amdgcn_mfma_f32_16x16x16_f16)
#define MFMA16(a, b, c) __builtin_amdgcn_mfma_f32_16x16x16_f16((a), (b), (c), 0, 0, 0)
#else
__device__ __forceinline__ f32x4 mfma16_fb(f16x4 a, f16x4 b, f32x4 c) {
    f16x8 a8 = {}, b8 = {};
#pragma unroll
    for (int i = 0; i < 4; ++i) { a8[i] = a[i]; b8[i] = b[i]; }
    return MFMA32(a8, b8, c);   // same (group,j) k-placement on both sides
}
#define MFMA16(a, b, c) mfma16_fb((a), (b), (c))
#endif

#if __has_builtin(__builtin_amdgcn_rsqf)
#define RSQ(x) __builtin_amdgcn_rsqf(x)
#else
#define RSQ(x) (1.0f / sqrtf(x))
#endif

#define CNT_OFF  0
#define W1A_OFF  40384       // f16[8][64][4]  (K16 A-frags of W1aug)
#define W2A_OFF  48576       // f16[24][64][8]
#define W3A_OFF  73152       // f16[3][64][8]
#define LIST_OFF 76224
#define TAU2     0.04f       // rescue if ||y||^2 < 0.2^2

__device__ __forceinline__ f16x8 pack_relu8(f32x4 d0, f32x4 d1, float zf) {
    union { f16x8 v; hf16x2 h[4]; } u;
    u.h[0] = __builtin_amdgcn_cvt_pkrtz(d0[0], d0[1]);
    u.h[1] = __builtin_amdgcn_cvt_pkrtz(d0[2], d0[3]);
    u.h[2] = __builtin_amdgcn_cvt_pkrtz(d1[0], d1[1]);
    u.h[3] = __builtin_amdgcn_cvt_pkrtz(d1[2], d1[3]);
    asm("v_pk_max_f16 %0, %0, %1" : "+v"(u.h[0]) : "v"(zf));
    asm("v_pk_max_f16 %0, %0, %1" : "+v"(u.h[1]) : "v"(zf));
    asm("v_pk_max_f16 %0, %0, %1" : "+v"(u.h[2]) : "v"(zf));
    asm("v_pk_max_f16 %0, %0, %1" : "+v"(u.h[3]) : "v"(zf));
    return u.v;
}

// ---------------- pack ----------------
__global__ __launch_bounds__(256) void pack_kernel(
    const float* __restrict__ W1, const float* __restrict__ b1,
    const float* __restrict__ W2, const float* __restrict__ b2,
    const float* __restrict__ W3, const float* __restrict__ b3,
    char* __restrict__ ws)
{
    int i = blockIdx.x * 256 + threadIdx.x;
    if (i == 0) *(unsigned int*)(ws + CNT_OFF) = 0u;
    _Float16* W1a = (_Float16*)(ws + W1A_OFF);
    _Float16* W2a = (_Float16*)(ws + W2A_OFF);
    _Float16* W3a = (_Float16*)(ws + W3A_OFF);

    // W1a[n][l][j]: K16 A-frag. feat = 16n + (l&15), k = (l>>4)*4 + j.
    if (i < 2048) {
        int n = i >> 8, l = (i >> 2) & 63, j = i & 3;
        int feat = 16*n + (l & 15);
        int k = (l >> 4) * 4 + j;
        float v = 0.f;
        if (feat < 120) {
            if (k < 5) v = W1[feat*5 + k];
            else if (k == 5) v = b1[feat];
        } else if (feat == 120 && k == 5) v = 1.f;
        W1a[i] = (_Float16)v;
    }
    // W2a[b=(n2*4+t4)][l][j']: k-perm f = 32*t4 + 16*(j'>>2) + 4*(l>>4) + (j'&3)
    if (i < 12288) {
        int b = i >> 9, l = (i >> 3) & 63, j = i & 7;
        int n2 = b >> 2, t4 = b & 3;
        int g = 16*n2 + (l & 15);
        int f = 32*t4 + 16*(j >> 2) + 4*(l >> 4) + (j & 3);
        float v = 0.f;
        if (g < 84) {
            if (f < 120) v = W2[g*120 + f];
            else if (f == 120) v = b2[g];
        } else if (g == 84 && f == 120) v = 1.f;
        W2a[i] = (_Float16)v;
    }
    // W3a[t3][l][j']: same k-perm over h2 features.
    if (i < 1536) {
        int t3 = i >> 9, l = (i >> 3) & 63, j = i & 7;
        int o = l & 15;
        int f = 32*t3 + 16*(j >> 2) + 4*(l >> 4) + (j & 3);
        float v = 0.f;
        if (o < 5) {
            if (f < 84) v = W3[o*84 + f];
            else if (f == 84) v = b3[o];
        }
        W3a[i] = (_Float16)v;
    }
}

// ---------------- main (persistent, zero-LDS, pipelined) ----------------
__global__ __launch_bounds__(256, 2) void mfma_main(
    const float* __restrict__ x, const char* __restrict__ ws,
    float* __restrict__ out,
    unsigned int* __restrict__ cnt, unsigned int* __restrict__ list,
    unsigned int cap, int nrows, int npairs)
{
    const _Float16* W1a = (const _Float16*)(ws + W1A_OFF);
    const _Float16* W2a = (const _Float16*)(ws + W2A_OFF);
    const _Float16* W3a = (const _Float16*)(ws + W3A_OFF);

    const int tid  = threadIdx.x;
    const int w    = tid >> 6, lane = tid & 63;
    const int c    = lane & 15, q = lane >> 4;
    const float zf = 0.f;

    // persistent weight fragments
    f16x4 w1f[8];
#pragma unroll
    for (int n = 0; n < 8; ++n)  w1f[n] = *(const f16x4*)(W1a + (n*64 + lane)*4);
    f16x8 w2f[24], w3f[3];
#pragma unroll
    for (int b = 0; b < 24; ++b) w2f[b] = *(const f16x8*)(W2a + (b*64 + lane)*8);
#pragma unroll
    for (int t = 0; t < 3; ++t)  w3f[t] = *(const f16x8*)(W3a + (t*64 + lane)*8);

    const int gw = blockIdx.x * 4 + w;
    const int nw = gridDim.x * 4;

    // ---- helpers inlined as lambdas ----
    auto LOADX = [&](int pair, float nxA[5], float nxB[5]) {
#pragma unroll
        for (int i = 0; i < 5; ++i) { nxA[i] = 0.f; nxB[i] = 0.f; }
        if (q == 0 && pair < npairs) {
            int rA = pair * 32 + c, rB = rA + 16;
            if (rA < nrows) {
                const float* xp = x + rA * 5;
                nxA[0]=xp[0]; nxA[1]=xp[1]; nxA[2]=xp[2]; nxA[3]=xp[3]; nxA[4]=xp[4];
            }
            if (rB < nrows) {
                const float* xp = x + rB * 5;
                nxB[0]=xp[0]; nxB[1]=xp[1]; nxB[2]=xp[2]; nxB[3]=xp[3]; nxB[4]=xp[4];
            }
        }
    };
    auto MAKEAX = [&](const float xA[5], const float xB[5],
                      f16x4& axA, f16x4& axB, int& mA, int& mB) {
        const float x4A = __shfl(xA[4], c, 64);   // q0's x4 to all q
        const float x4B = __shfl(xB[4], c, 64);
        union { f16x4 v; hf16x2 h[2]; } ua, ub;
        float aA0 = (q == 0) ? xA[0] : ((q == 1) ? x4A : 0.f);
        float aA1 = (q == 0) ? xA[1] : ((q == 1) ? 1.f  : 0.f);
        float aA2 = (q == 0) ? xA[2] : 0.f;
        float aA3 = (q == 0) ? xA[3] : 0.f;
        float aB0 = (q == 0) ? xB[0] : ((q == 1) ? x4B : 0.f);
        float aB1 = (q == 0) ? xB[1] : ((q == 1) ? 1.f  : 0.f);
        float aB2 = (q == 0) ? xB[2] : 0.f;
        float aB3 = (q == 0) ? xB[3] : 0.f;
        ua.h[0] = __builtin_amdgcn_cvt_pkrtz(aA0, aA1);
        ua.h[1] = __builtin_amdgcn_cvt_pkrtz(aA2, aA3);
        ub.h[0] = __builtin_amdgcn_cvt_pkrtz(aB0, aB1);
        ub.h[1] = __builtin_amdgcn_cvt_pkrtz(aB2, aB3);
        axA = ua.v; axB = ub.v;
        mA = (int)(xA[0] != 0.f)       | ((int)(xA[1] != 0.f) << 1)
           | ((int)(xA[2] != 0.f) << 2) | ((int)(xA[3] != 0.f) << 3)
           | ((int)(xA[4] != 0.f) << 4);
        mB = (int)(xB[0] != 0.f)       | ((int)(xB[1] != 0.f) << 1)
           | ((int)(xB[2] != 0.f) << 2) | ((int)(xB[3] != 0.f) << 3)
           | ((int)(xB[4] != 0.f) << 4);
    };
    auto L1PACK = [&](f16x4 axA, f16x4 axB, f16x8 pbA[4], f16x8 pbB[4]) {
#pragma unroll
        for (int t4 = 0; t4 < 4; ++t4) {
            f32x4 dA0 = MFMA16(w1f[2*t4],     axA, FZERO);
            f32x4 dB0 = MFMA16(w1f[2*t4],     axB, FZERO);
            f32x4 dA1 = MFMA16(w1f[2*t4 + 1], axA, FZERO);
            f32x4 dB1 = MFMA16(w1f[2*t4 + 1], axB, FZERO);
            pbA[t4] = pack_relu8(dA0, dA1, zf);
            pbB[t4] = pack_relu8(dB0, dB1, zf);
        }
    };

    // ---- prologue: pair gw fully staged ----
    float nxA[5], nxB[5];
    f16x8 pbA[4], pbB[4];
    int mA = 0, mB = 0;
    {
        LOADX(gw, nxA, nxB);
        f16x4 axA, axB;
        MAKEAX(nxA, nxB, axA, axB, mA, mB);
        L1PACK(axA, axB, pbA, pbB);
        LOADX(gw + nw, nxA, nxB);     // prefetch pair gw+nw
    }

    for (int p = gw; p < npairs; p += nw) {
        const int rowA = p * 32 + c;
        const int rowB = rowA + 16;
        const bool validA = (q == 0) && (rowA < nrows);
        const bool validB = (q == 0) && (rowB < nrows);

        // ---- L2 (current) ----
        __builtin_amdgcn_s_setprio(1);
        f32x4 accA[6], accB[6];
#pragma unroll
        for (int n2 = 0; n2 < 6; ++n2) {
            accA[n2] = MFMA32(w2f[n2*4 + 0], pbA[0], FZERO);
            accB[n2] = MFMA32(w2f[n2*4 + 0], pbB[0], FZERO);
        }
#pragma unroll
        for (int t4 = 1; t4 < 4; ++t4)
#pragma unroll
            for (int n2 = 0; n2 < 6; ++n2) {
                accA[n2] = MFMA32(w2f[n2*4 + t4], pbA[t4], accA[n2]);
                accB[n2] = MFMA32(w2f[n2*4 + t4], pbB[t4], accB[n2]);
            }
        __builtin_amdgcn_s_setprio(0);

        // ---- stage NEXT pair: consume in-flight x, reissue prefetch ----
        f16x4 axNA, axNB; int mNA, mNB;
        MAKEAX(nxA, nxB, axNA, axNB, mNA, mNB);
        LOADX(p + 2*nw, nxA, nxB);

        // ---- pack h2 + L3 (current) ----
        f16x8 phA[3], phB[3];
#pragma unroll
        for (int t3 = 0; t3 < 3; ++t3) {
            phA[t3] = pack_relu8(accA[2*t3], accA[2*t3 + 1], zf);
            phB[t3] = pack_relu8(accB[2*t3], accB[2*t3 + 1], zf);
        }
        __builtin_amdgcn_s_setprio(1);
        f32x4 acyA = MFMA32(w3f[0], phA[0], FZERO);
        f32x4 acyB = MFMA32(w3f[0], phB[0], FZERO);
#pragma unroll
        for (int t3 = 1; t3 < 3; ++t3) {
            acyA = MFMA32(w3f[t3], phA[t3], acyA);
            acyB = MFMA32(w3f[t3], phB[t3], acyB);
        }
        __builtin_amdgcn_s_setprio(0);

        // ---- L1 (next pair): independent MFMAs fill L3's latency ----
        f16x8 pbNA[4], pbNB[4];
        L1PACK(axNA, axNB, pbNA, pbNB);

        // ---- epilogue (current) ----
        float rA0 = fmaxf(acyA[0], 0.f);
        float rB0 = fmaxf(acyB[0], 0.f);
        float y4A = __shfl(rA0, c + 16, 64);   // out4 lives in q==1, j==0
        float y4B = __shfl(rB0, c + 16, 64);
        if (validA) {
            float y0 = rA0;
            float y1 = fmaxf(acyA[1], 0.f);
            float y2 = fmaxf(acyA[2], 0.f);
            float y3 = fmaxf(acyA[3], 0.f);
            float ss = y0*y0 + y1*y1 + y2*y2 + y3*y3 + y4A*y4A;
            float inv = RSQ(fmaxf(ss, 1e-30f));  // rescued rows overwritten
            float* op = out + rowA * 5;
            op[0] = (mA & 1)  ? 0.f : y0 * inv;
            op[1] = (mA & 2)  ? 0.f : y1 * inv;
            op[2] = (mA & 4)  ? 0.f : y2 * inv;
            op[3] = (mA & 8)  ? 0.f : y3 * inv;
            op[4] = (mA & 16) ? 0.f : y4A * inv;
            if (ss < TAU2) {
                unsigned int idx = atomicAdd(cnt, 1u);
                if (idx < cap) list[idx] = (unsigned int)rowA;
            }
        }
        if (validB) {
            float y0 = rB0;
            float y1 = fmaxf(acyB[1], 0.f);
            float y2 = fmaxf(acyB[2], 0.f);
            float y3 = fmaxf(acyB[3], 0.f);
            float ss = y0*y0 + y1*y1 + y2*y2 + y3*y3 + y4B*y4B;
            float inv = RSQ(fmaxf(ss, 1e-30f));
            float* op = out + rowB * 5;
            op[0] = (mB & 1)  ? 0.f : y0 * inv;
            op[1] = (mB & 2)  ? 0.f : y1 * inv;
            op[2] = (mB & 4)  ? 0.f : y2 * inv;
            op[3] = (mB & 8)  ? 0.f : y3 * inv;
            op[4] = (mB & 16) ? 0.f : y4B * inv;
            if (ss < TAU2) {
                unsigned int idx = atomicAdd(cnt, 1u);
                if (idx < cap) list[idx] = (unsigned int)rowB;
            }
        }

        // ---- rotate pipeline state ----
#pragma unroll
        for (int t = 0; t < 4; ++t) { pbA[t] = pbNA[t]; pbB[t] = pbNB[t]; }
        mA = mNA; mB = mNB;
    }
}

// ---------------- rescue (exact f32, WAVE-parallel: 1 wave per row) -------
__global__ __launch_bounds__(256) void rescue_kernel(
    const float* __restrict__ x,
    const float* __restrict__ W1, const float* __restrict__ b1,
    const float* __restrict__ W2, const float* __restrict__ b2,
    const float* __restrict__ W3, const float* __restrict__ b3,
    const char* __restrict__ ws, float* __restrict__ out,
    unsigned int cap, int nrows)
{
    const unsigned int* cnt  = (const unsigned int*)(ws + CNT_OFF);
    const unsigned int* list = (const unsigned int*)(ws + LIST_OFF);
    unsigned int count = *cnt;
    if (count > cap) count = cap;

    const int lane   = threadIdx.x & 63;
    const int wid    = (blockIdx.x * 256 + threadIdx.x) >> 6;
    const int nwaves = (gridDim.x * 256) >> 6;

    const int g1 = lane;
    const bool has2 = (lane < 20);
    const int g2 = has2 ? (64 + lane) : 0;

    for (unsigned int t = wid; t < count; t += nwaves) {
        long row = (long)list[t];
        if (row < 0 || row >= (long)nrows) continue;   // replay-safety guard

        const float* xr = x + row * 5;
        const float xv0 = xr[0], xv1 = xr[1], xv2 = xr[2],
                    xv3 = xr[3], xv4 = xr[4];

        float acc1 = b2[g1];
        float acc2 = has2 ? b2[g2] : 0.f;
        const float* w2r1 = W2 + (size_t)g1 * 120;
        const float* w2r2 = W2 + (size_t)g2 * 120;
        for (int h = 0; h < 120; ++h) {
            float a = b1[h];
            a = fmaf(W1[h*5 + 0], xv0, a);
            a = fmaf(W1[h*5 + 1], xv1, a);
            a = fmaf(W1[h*5 + 2], xv2, a);
            a = fmaf(W1[h*5 + 3], xv3, a);
            a = fmaf(W1[h*5 + 4], xv4, a);
            a = fmaxf(a, 0.0f);
            acc1 = fmaf(w2r1[h], a, acc1);
            acc2 = fmaf(w2r2[h], a, acc2);
        }
        float h2a = fmaxf(acc1, 0.f);
        float h2b = has2 ? fmaxf(acc2, 0.f) : 0.f;

        float y[5];
#pragma unroll
        for (int o = 0; o < 5; ++o) {
            float p = W3[o*84 + g1] * h2a;
            if (has2) p = fmaf(W3[o*84 + g2], h2b, p);
#pragma unroll
            for (int s = 1; s < 64; s <<= 1) p += __shfl_xor(p, s, 64);
            y[o] = fmaxf(p + b3[o], 0.f);
        }

        if (lane == 0) {
            float ss = y[0]*y[0];
            ss = fmaf(y[1], y[1], ss);
            ss = fmaf(y[2], y[2], ss);
            ss = fmaf(y[3], y[3], ss);
            ss = fmaf(y[4], y[4], ss);
            float inv = 1.0f / fmaxf(sqrtf(ss), 1e-12f);
            float* op = out + row * 5;
#pragma unroll
            for (int o = 0; o < 5; ++o)
                op[o] = (xr[o] != 0.f) ? 0.f : y[o] * inv;
        }
    }
}

// ---------------- launch ----------------
extern "C" void kernel_launch(void* const* d_in, const int* in_sizes, int n_in,
                              void* d_out, int out_size, void* d_ws, size_t ws_size,
                              hipStream_t stream) {
    const float* x  = (const float*)d_in[0];
    const float* W1 = (const float*)d_in[1];
    const float* b1 = (const float*)d_in[2];
    const float* W2 = (const float*)d_in[3];
    const float* b2 = (const float*)d_in[4];
    const float* W3 = (const float*)d_in[5];
    const float* b3 = (const float*)d_in[6];
    float* out = (float*)d_out;
    char* ws = (char*)d_ws;

    const int nrows = in_sizes[0] / 5;
    const int ntiles = (nrows + 15) / 16;
    const int npairs = (ntiles + 1) / 2;
    unsigned int cap = (ws_size > (size_t)LIST_OFF + 4)
                       ? (unsigned int)((ws_size - LIST_OFF) / 4) : 0u;
    unsigned int* cnt  = (unsigned int*)(ws + CNT_OFF);
    unsigned int* list = (unsigned int*)(ws + LIST_OFF);

    pack_kernel<<<48, 256, 0, stream>>>(W1, b1, W2, b2, W3, b3, ws);

    mfma_main<<<512, 256, 0, stream>>>(x, ws, out, cnt, list, cap,
                                       nrows, npairs);

    rescue_kernel<<<256, 256, 0, stream>>>(x, W1, b1, W2, b2, W3, b3,
                                           ws, out, cap, nrows);
}

// Round 19
// 66.237 us; speedup vs baseline: 1.0272x; 1.0272x over previous
//
#include <hip/hip_runtime.h>

// Per-row MLP 5->120->84->5 + relu + L2-normalize + x!=0 mask.
// R19 = exact revert to R17 (best measured: 66.0 us total, main ~54.5 us).
// R18's explicit cross-pair pipeline regressed (-8%): the compiler already
// hoists next-pair LOADX/MAKEAX across the back-edge; manual rotation added
// ~16 reg-copies/iter + VGPR pressure (116->120) for nothing.
// Structure: K16 L1, cvt_pkrtz + v_pk_max_f16 packs, zero-C-born accs,
// 2-tile interleave, zero-LDS, register/AGPR-resident weights (2 waves/SIMD
// by design), rsq epilogue, setprio on MFMA clusters, wave-parallel f32
// rescue for ||y|| < 0.2 rows.

typedef _Float16 f16x8 __attribute__((ext_vector_type(8)));
typedef _Float16 f16x4 __attribute__((ext_vector_type(4)));
typedef __fp16   hf16x2 __attribute__((ext_vector_type(2)));
typedef float    f32x4 __attribute__((ext_vector_type(4)));

#if __has_builtin(__builtin_amdgcn_mfma_f32_16x16x16f16)
#define HAVE_K16 1
#define MFMA16(a, b, c) __builtin_amdgcn_mfma_f32_16x16x16f16((a), (b), (c), 0, 0, 0)
#elif __has_builtin(__builtin_amdgcn_mfma_f32_16x16x16_f16)
#define HAVE_K16 1
#define MFMA16(a, b, c) __builtin_amdgcn_mfma_f32_16x16x16_f16((a), (b), (c), 0, 0, 0)
#else
#define HAVE_K16 0
#endif
#define MFMA32(a, b, c) __builtin_amdgcn_mfma_f32_16x16x32_f16((a), (b), (c), 0, 0, 0)
#define FZERO ((f32x4){0.f, 0.f, 0.f, 0.f})

#if __has_builtin(__builtin_amdgcn_rsqf)
#define RSQ(x) __builtin_amdgcn_rsqf(x)
#else
#define RSQ(x) (1.0f / sqrtf(x))
#endif

#define CNT_OFF  0
#define W1A_OFF  40384       // K16: f16[8][64][4]; K32: f16[8][64][8]
#define W2A_OFF  48576       // f16[24][64][8]       -> ends 73152
#define W3A_OFF  73152       // f16[3][64][8]        -> ends 76224
#define LIST_OFF 76224
#define TAU2     0.04f       // rescue if ||y||^2 < 0.2^2

// cvt then packed-f16 relu: 4 cvt + 4 v_pk_max_f16.
__device__ __forceinline__ f16x8 pack_relu8(f32x4 d0, f32x4 d1, float zf) {
    union { f16x8 v; hf16x2 h[4]; } u;
    u.h[0] = __builtin_amdgcn_cvt_pkrtz(d0[0], d0[1]);
    u.h[1] = __builtin_amdgcn_cvt_pkrtz(d0[2], d0[3]);
    u.h[2] = __builtin_amdgcn_cvt_pkrtz(d1[0], d1[1]);
    u.h[3] = __builtin_amdgcn_cvt_pkrtz(d1[2], d1[3]);
    asm("v_pk_max_f16 %0, %0, %1" : "+v"(u.h[0]) : "v"(zf));
    asm("v_pk_max_f16 %0, %0, %1" : "+v"(u.h[1]) : "v"(zf));
    asm("v_pk_max_f16 %0, %0, %1" : "+v"(u.h[2]) : "v"(zf));
    asm("v_pk_max_f16 %0, %0, %1" : "+v"(u.h[3]) : "v"(zf));
    return u.v;
}

// ---------------- pack ----------------
__global__ __launch_bounds__(256) void pack_kernel(
    const float* __restrict__ W1, const float* __restrict__ b1,
    const float* __restrict__ W2, const float* __restrict__ b2,
    const float* __restrict__ W3, const float* __restrict__ b3,
    char* __restrict__ ws)
{
    int i = blockIdx.x * 256 + threadIdx.x;
    if (i == 0) *(unsigned int*)(ws + CNT_OFF) = 0u;
    _Float16* W1a = (_Float16*)(ws + W1A_OFF);
    _Float16* W2a = (_Float16*)(ws + W2A_OFF);
    _Float16* W3a = (_Float16*)(ws + W3A_OFF);

#if HAVE_K16
    // W1a[n][l][j]: K16 A-frag. feat = 16n + (l&15), k = (l>>4)*4 + j.
    if (i < 2048) {
        int n = i >> 8, l = (i >> 2) & 63, j = i & 3;
        int feat = 16*n + (l & 15);
        int k = (l >> 4) * 4 + j;
        float v = 0.f;
        if (feat < 120) {
            if (k < 5) v = W1[feat*5 + k];
            else if (k == 5) v = b1[feat];
        } else if (feat == 120 && k == 5) v = 1.f;
        W1a[i] = (_Float16)v;
    }
#else
    if (i < 4096) {
        int n = i >> 9, l = (i >> 3) & 63, j = i & 7;
        int feat = 16*n + (l & 15);
        int k = (l >> 4) * 8 + j;
        float v = 0.f;
        if (feat < 120) {
            if (k < 5) v = W1[feat*5 + k];
            else if (k == 5) v = b1[feat];
        } else if (feat == 120 && k == 5) v = 1.f;
        W1a[i] = (_Float16)v;
    }
#endif
    // W2a[b=(n2*4+t4)][l][j']: A-frag of W2aug, k-permuted:
    //   f = 32*t4 + 16*(j'>>2) + 4*(l>>4) + (j'&3)
    if (i < 12288) {
        int b = i >> 9, l = (i >> 3) & 63, j = i & 7;
        int n2 = b >> 2, t4 = b & 3;
        int g = 16*n2 + (l & 15);
        int f = 32*t4 + 16*(j >> 2) + 4*(l >> 4) + (j & 3);
        float v = 0.f;
        if (g < 84) {
            if (f < 120) v = W2[g*120 + f];
            else if (f == 120) v = b2[g];
        } else if (g == 84 && f == 120) v = 1.f;
        W2a[i] = (_Float16)v;
    }
    // W3a[t3][l][j']: same k-permutation over h2 features.
    if (i < 1536) {
        int t3 = i >> 9, l = (i >> 3) & 63, j = i & 7;
        int o = l & 15;
        int f = 32*t3 + 16*(j >> 2) + 4*(l >> 4) + (j & 3);
        float v = 0.f;
        if (o < 5) {
            if (f < 84) v = W3[o*84 + f];
            else if (f == 84) v = b3[o];
        }
        W3a[i] = (_Float16)v;
    }
}

// ---------------- main (persistent, zero-LDS, 2-tile interleave) ----------
__global__ __launch_bounds__(256, 2) void mfma_main(
    const float* __restrict__ x, const char* __restrict__ ws,
    float* __restrict__ out,
    unsigned int* __restrict__ cnt, unsigned int* __restrict__ list,
    unsigned int cap, int nrows, int npairs)
{
    const _Float16* W1a = (const _Float16*)(ws + W1A_OFF);
    const _Float16* W2a = (const _Float16*)(ws + W2A_OFF);
    const _Float16* W3a = (const _Float16*)(ws + W3A_OFF);

    const int tid  = threadIdx.x;
    const int w    = tid >> 6, lane = tid & 63;
    const int c    = lane & 15, q = lane >> 4;
    const float zf = 0.f;      // shared zero reg for v_pk_max_f16

    // persistent weight fragments (loaded once per wave)
#if HAVE_K16
    f16x4 w1f[8];
#pragma unroll
    for (int n = 0; n < 8; ++n)  w1f[n] = *(const f16x4*)(W1a + (n*64 + lane)*4);
#else
    f16x8 w1f[8];
#pragma unroll
    for (int n = 0; n < 8; ++n)  w1f[n] = *(const f16x8*)(W1a + (n*64 + lane)*8);
#endif
    f16x8 w2f[24], w3f[3];
#pragma unroll
    for (int b = 0; b < 24; ++b) w2f[b] = *(const f16x8*)(W2a + (b*64 + lane)*8);
#pragma unroll
    for (int t = 0; t < 3; ++t)  w3f[t] = *(const f16x8*)(W3a + (t*64 + lane)*8);

    const int gw = blockIdx.x * 4 + w;
    const int nw = gridDim.x * 4;

    // prefetch x for the first pair (tiles 2p and 2p+1 -> rows 32p+c, +16)
    float nxA[5] = {0.f, 0.f, 0.f, 0.f, 0.f};
    float nxB[5] = {0.f, 0.f, 0.f, 0.f, 0.f};
    if (q == 0 && gw < npairs) {
        int rA = gw * 32 + c;
        int rB = rA + 16;
        if (rA < nrows) {
            const float* xp = x + rA * 5;
            nxA[0]=xp[0]; nxA[1]=xp[1]; nxA[2]=xp[2]; nxA[3]=xp[3]; nxA[4]=xp[4];
        }
        if (rB < nrows) {
            const float* xp = x + rB * 5;
            nxB[0]=xp[0]; nxB[1]=xp[1]; nxB[2]=xp[2]; nxB[3]=xp[3]; nxB[4]=xp[4];
        }
    }

    for (int p = gw; p < npairs; p += nw) {
        const int rowA = p * 32 + c;
        const int rowB = rowA + 16;
        const bool validA = (q == 0) && (rowA < nrows);
        const bool validB = (q == 0) && (rowB < nrows);

        // consume prefetched x
        float xA[5], xB[5];
#pragma unroll
        for (int i = 0; i < 5; ++i) { xA[i] = nxA[i]; xB[i] = nxB[i]; }

        // issue next pair's loads now (hidden under this pair's compute)
#pragma unroll
        for (int i = 0; i < 5; ++i) { nxA[i] = 0.f; nxB[i] = 0.f; }
        {
            const int pn = p + nw;
            if (q == 0 && pn < npairs) {
                int rA = pn * 32 + c;
                int rB = rA + 16;
                if (rA < nrows) {
                    const float* xp = x + rA * 5;
                    nxA[0]=xp[0]; nxA[1]=xp[1]; nxA[2]=xp[2]; nxA[3]=xp[3]; nxA[4]=xp[4];
                }
                if (rB < nrows) {
                    const float* xp = x + rB * 5;
                    nxB[0]=xp[0]; nxB[1]=xp[1]; nxB[2]=xp[2]; nxB[3]=xp[3]; nxB[4]=xp[4];
                }
            }
        }

#if HAVE_K16
        // K16 B-frag: lane holds xaug[c][k=q*4+j].
        // q==0: [x0,x1,x2,x3]; q==1: [x4, 1, 0, 0]; else 0.
        const float x4A = __shfl(xA[4], c, 64);   // broadcast q0's x4 to all q
        const float x4B = __shfl(xB[4], c, 64);
        f16x4 axA, axB;
        {
            union { f16x4 v; hf16x2 h[2]; } ua, ub;
            float aA0 = (q == 0) ? xA[0] : ((q == 1) ? x4A : 0.f);
            float aA1 = (q == 0) ? xA[1] : ((q == 1) ? 1.f  : 0.f);
            float aA2 = (q == 0) ? xA[2] : 0.f;
            float aA3 = (q == 0) ? xA[3] : 0.f;
            float aB0 = (q == 0) ? xB[0] : ((q == 1) ? x4B : 0.f);
            float aB1 = (q == 0) ? xB[1] : ((q == 1) ? 1.f  : 0.f);
            float aB2 = (q == 0) ? xB[2] : 0.f;
            float aB3 = (q == 0) ? xB[3] : 0.f;
            ua.h[0] = __builtin_amdgcn_cvt_pkrtz(aA0, aA1);
            ua.h[1] = __builtin_amdgcn_cvt_pkrtz(aA2, aA3);
            ub.h[0] = __builtin_amdgcn_cvt_pkrtz(aB0, aB1);
            ub.h[1] = __builtin_amdgcn_cvt_pkrtz(aB2, aB3);
            axA = ua.v; axB = ub.v;
        }
#else
        f16x8 axA, axB;
#pragma unroll
        for (int j = 0; j < 8; ++j) { axA[j] = (_Float16)0.f; axB[j] = (_Float16)0.f; }
        if (validA) {
            axA[0]=(_Float16)xA[0]; axA[1]=(_Float16)xA[1]; axA[2]=(_Float16)xA[2];
            axA[3]=(_Float16)xA[3]; axA[4]=(_Float16)xA[4]; axA[5]=(_Float16)1.f;
        }
        if (validB) {
            axB[0]=(_Float16)xB[0]; axB[1]=(_Float16)xB[1]; axB[2]=(_Float16)xB[2];
            axB[3]=(_Float16)xB[3]; axB[4]=(_Float16)xB[4]; axB[5]=(_Float16)1.f;
        }
#endif

        // ---- L1 + fused h1-pack: pb*[t4] (feat = 16n + 4q + j) ----
        f16x8 pbA[4], pbB[4];
#pragma unroll
        for (int t4 = 0; t4 < 4; ++t4) {
#if HAVE_K16
            f32x4 dA0 = MFMA16(w1f[2*t4],     axA, FZERO);
            f32x4 dB0 = MFMA16(w1f[2*t4],     axB, FZERO);
            f32x4 dA1 = MFMA16(w1f[2*t4 + 1], axA, FZERO);
            f32x4 dB1 = MFMA16(w1f[2*t4 + 1], axB, FZERO);
#else
            f32x4 dA0 = MFMA32(w1f[2*t4],     axA, FZERO);
            f32x4 dB0 = MFMA32(w1f[2*t4],     axB, FZERO);
            f32x4 dA1 = MFMA32(w1f[2*t4 + 1], axA, FZERO);
            f32x4 dB1 = MFMA32(w1f[2*t4 + 1], axB, FZERO);
#endif
            pbA[t4] = pack_relu8(dA0, dA1, zf);
            pbB[t4] = pack_relu8(dB0, dB1, zf);
        }

        // ---- L2: acc*[n2] = W2aug . h1^T ; first MFMA born from zero-C ----
        __builtin_amdgcn_s_setprio(1);
        f32x4 accA[6], accB[6];
#pragma unroll
        for (int n2 = 0; n2 < 6; ++n2) {
            accA[n2] = MFMA32(w2f[n2*4 + 0], pbA[0], FZERO);
            accB[n2] = MFMA32(w2f[n2*4 + 0], pbB[0], FZERO);
        }
#pragma unroll
        for (int t4 = 1; t4 < 4; ++t4)
#pragma unroll
            for (int n2 = 0; n2 < 6; ++n2) {
                accA[n2] = MFMA32(w2f[n2*4 + t4], pbA[t4], accA[n2]);
                accB[n2] = MFMA32(w2f[n2*4 + t4], pbB[t4], accB[n2]);
            }
        __builtin_amdgcn_s_setprio(0);

        // ---- pack h2 B-frags ----
        f16x8 phA[3], phB[3];
#pragma unroll
        for (int t3 = 0; t3 < 3; ++t3) {
            phA[t3] = pack_relu8(accA[2*t3], accA[2*t3 + 1], zf);
            phB[t3] = pack_relu8(accB[2*t3], accB[2*t3 + 1], zf);
        }

        // ---- L3 (first MFMA born from zero-C) ----
        __builtin_amdgcn_s_setprio(1);
        f32x4 acyA = MFMA32(w3f[0], phA[0], FZERO);
        f32x4 acyB = MFMA32(w3f[0], phB[0], FZERO);
#pragma unroll
        for (int t3 = 1; t3 < 3; ++t3) {
            acyA = MFMA32(w3f[t3], phA[t3], acyA);
            acyB = MFMA32(w3f[t3], phB[t3], acyB);
        }
        __builtin_amdgcn_s_setprio(0);

        // ---- epilogue (both tiles) ----
        float rA0 = fmaxf(acyA[0], 0.f);
        float rB0 = fmaxf(acyB[0], 0.f);
        float y4A = __shfl(rA0, c + 16, 64);   // out4 lives in q==1, j==0
        float y4B = __shfl(rB0, c + 16, 64);
        if (validA) {
            float y0 = rA0;
            float y1 = fmaxf(acyA[1], 0.f);
            float y2 = fmaxf(acyA[2], 0.f);
            float y3 = fmaxf(acyA[3], 0.f);
            float ss = y0*y0 + y1*y1 + y2*y2 + y3*y3 + y4A*y4A;
            float inv = RSQ(fmaxf(ss, 1e-30f));  // rescued rows overwritten
            float* op = out + rowA * 5;
            op[0] = (xA[0] != 0.f) ? 0.f : y0 * inv;
            op[1] = (xA[1] != 0.f) ? 0.f : y1 * inv;
            op[2] = (xA[2] != 0.f) ? 0.f : y2 * inv;
            op[3] = (xA[3] != 0.f) ? 0.f : y3 * inv;
            op[4] = (xA[4] != 0.f) ? 0.f : y4A * inv;
            if (ss < TAU2) {
                unsigned int idx = atomicAdd(cnt, 1u);
                if (idx < cap) list[idx] = (unsigned int)rowA;
            }
        }
        if (validB) {
            float y0 = rB0;
            float y1 = fmaxf(acyB[1], 0.f);
            float y2 = fmaxf(acyB[2], 0.f);
            float y3 = fmaxf(acyB[3], 0.f);
            float ss = y0*y0 + y1*y1 + y2*y2 + y3*y3 + y4B*y4B;
            float inv = RSQ(fmaxf(ss, 1e-30f));
            float* op = out + rowB * 5;
            op[0] = (xB[0] != 0.f) ? 0.f : y0 * inv;
            op[1] = (xB[1] != 0.f) ? 0.f : y1 * inv;
            op[2] = (xB[2] != 0.f) ? 0.f : y2 * inv;
            op[3] = (xB[3] != 0.f) ? 0.f : y3 * inv;
            op[4] = (xB[4] != 0.f) ? 0.f : y4B * inv;
            if (ss < TAU2) {
                unsigned int idx = atomicAdd(cnt, 1u);
                if (idx < cap) list[idx] = (unsigned int)rowB;
            }
        }
    }
}

// ---------------- rescue (exact f32, WAVE-parallel: 1 wave per row) -------
__global__ __launch_bounds__(256) void rescue_kernel(
    const float* __restrict__ x,
    const float* __restrict__ W1, const float* __restrict__ b1,
    const float* __restrict__ W2, const float* __restrict__ b2,
    const float* __restrict__ W3, const float* __restrict__ b3,
    const char* __restrict__ ws, float* __restrict__ out,
    unsigned int cap, int nrows)
{
    const unsigned int* cnt  = (const unsigned int*)(ws + CNT_OFF);
    const unsigned int* list = (const unsigned int*)(ws + LIST_OFF);
    unsigned int count = *cnt;
    if (count > cap) count = cap;

    const int lane   = threadIdx.x & 63;
    const int wid    = (blockIdx.x * 256 + threadIdx.x) >> 6;
    const int nwaves = (gridDim.x * 256) >> 6;

    const int g1 = lane;                        // h2 output 0..63
    const bool has2 = (lane < 20);
    const int g2 = has2 ? (64 + lane) : 0;      // h2 output 64..83 (clamped)

    for (unsigned int t = wid; t < count; t += nwaves) {
        long row = (long)list[t];
        if (row < 0 || row >= (long)nrows) continue;   // replay-safety guard

        const float* xr = x + row * 5;                 // uniform across wave
        const float xv0 = xr[0], xv1 = xr[1], xv2 = xr[2],
                    xv3 = xr[3], xv4 = xr[4];

        // h2[g] = relu(b2[g] + sum_h W2[g][h] * relu(W1[h].x + b1[h]))
        float acc1 = b2[g1];
        float acc2 = has2 ? b2[g2] : 0.f;
        const float* w2r1 = W2 + (size_t)g1 * 120;
        const float* w2r2 = W2 + (size_t)g2 * 120;
        for (int h = 0; h < 120; ++h) {
            float a = b1[h];
            a = fmaf(W1[h*5 + 0], xv0, a);
            a = fmaf(W1[h*5 + 1], xv1, a);
            a = fmaf(W1[h*5 + 2], xv2, a);
            a = fmaf(W1[h*5 + 3], xv3, a);
            a = fmaf(W1[h*5 + 4], xv4, a);
            a = fmaxf(a, 0.0f);                        // h1[h], uniform
            acc1 = fmaf(w2r1[h], a, acc1);
            acc2 = fmaf(w2r2[h], a, acc2);             // branch-free (clamped)
        }
        float h2a = fmaxf(acc1, 0.f);
        float h2b = has2 ? fmaxf(acc2, 0.f) : 0.f;

        // y[o] = relu(b3[o] + sum_g W3[o][g] * h2[g]) via wave reduction
        float y[5];
#pragma unroll
        for (int o = 0; o < 5; ++o) {
            float p = W3[o*84 + g1] * h2a;
            if (has2) p = fmaf(W3[o*84 + g2], h2b, p);
#pragma unroll
            for (int s = 1; s < 64; s <<= 1) p += __shfl_xor(p, s, 64);
            y[o] = fmaxf(p + b3[o], 0.f);
        }

        if (lane == 0) {
            float ss = y[0]*y[0];
            ss = fmaf(y[1], y[1], ss);
            ss = fmaf(y[2], y[2], ss);
            ss = fmaf(y[3], y[3], ss);
            ss = fmaf(y[4], y[4], ss);
            float inv = 1.0f / fmaxf(sqrtf(ss), 1e-12f);
            float* op = out + row * 5;
#pragma unroll
            for (int o = 0; o < 5; ++o)
                op[o] = (xr[o] != 0.f) ? 0.f : y[o] * inv;
        }
    }
}

// ---------------- launch ----------------
extern "C" void kernel_launch(void* const* d_in, const int* in_sizes, int n_in,
                              void* d_out, int out_size, void* d_ws, size_t ws_size,
                              hipStream_t stream) {
    const float* x  = (const float*)d_in[0];
    const float* W1 = (const float*)d_in[1];
    const float* b1 = (const float*)d_in[2];
    const float* W2 = (const float*)d_in[3];
    const float* b2 = (const float*)d_in[4];
    const float* W3 = (const float*)d_in[5];
    const float* b3 = (const float*)d_in[6];
    float* out = (float*)d_out;
    char* ws = (char*)d_ws;

    const int nrows = in_sizes[0] / 5;
    const int ntiles = (nrows + 15) / 16;
    const int npairs = (ntiles + 1) / 2;
    unsigned int cap = (ws_size > (size_t)LIST_OFF + 4)
                       ? (unsigned int)((ws_size - LIST_OFF) / 4) : 0u;
    unsigned int* cnt  = (unsigned int*)(ws + CNT_OFF);
    unsigned int* list = (unsigned int*)(ws + LIST_OFF);

    pack_kernel<<<48, 256, 0, stream>>>(W1, b1, W2, b2, W3, b3, ws);

    mfma_main<<<512, 256, 0, stream>>>(x, ws, out, cnt, list, cap,
                                       nrows, npairs);

    rescue_kernel<<<256, 256, 0, stream>>>(x, W1, b1, W2, b2, W3, b3,
                                           ws, out, cap, nrows);
}